// Round 9
// baseline (565.225 us; speedup 1.0000x reference)
//
#include <hip/hip_runtime.h>

#define D 128
#define RMAX 16

typedef short s16x8 __attribute__((ext_vector_type(8)));
typedef float f32x4 __attribute__((ext_vector_type(4)));

__device__ inline unsigned short f2b(float f) {
    unsigned u = __builtin_bit_cast(unsigned, f);
    unsigned r = (u + 0x7FFFu + ((u >> 16) & 1u)) >> 16;
    return (unsigned short)r;
}
__device__ inline float b2f(unsigned short h) {
    unsigned u = ((unsigned)h) << 16;
    return __builtin_bit_cast(float, u);
}

// ---------------- histogram: deg[r*N+dst] ----------------

__global__ void k_count2(const int* __restrict__ etype, const int* __restrict__ dstA,
                         int E, int N, int* __restrict__ deg) {
    int e = blockIdx.x * blockDim.x + threadIdx.x;
    if (e < E) atomicAdd(&deg[etype[e] * N + dstA[e]], 1);
}

// ---------------- generic scans (exclusive, over R*N) ----------------

template<int VPT>
__global__ void k_scan_blk(const int* __restrict__ in, int* __restrict__ tmp,
                           int* __restrict__ bsum, int n) {
    __shared__ int sd[256];
    int t = threadIdx.x;
    long base = (long)blockIdx.x * (256 * VPT) + (long)t * VPT;
    int s[VPT];
    int tsum = 0;
    #pragma unroll
    for (int k = 0; k < VPT; ++k) { s[k] = (base + k < n) ? in[base + k] : 0; tsum += s[k]; }
    sd[t] = tsum;
    __syncthreads();
    for (int off = 1; off < 256; off <<= 1) {
        int v = (t >= off) ? sd[t - off] : 0;
        __syncthreads();
        sd[t] += v;
        __syncthreads();
    }
    int run = sd[t] - tsum;
    #pragma unroll
    for (int k = 0; k < VPT; ++k) { if (base + k < n) tmp[base + k] = run; run += s[k]; }
    if (t == 255) bsum[blockIdx.x] = sd[255];
}

__global__ void k_scan2(const int* __restrict__ bsum, int* __restrict__ boff, int nb) {
    __shared__ int sd[256];
    int t = threadIdx.x;
    int v = (t < nb) ? bsum[t] : 0;
    sd[t] = v;
    __syncthreads();
    for (int off = 1; off < 256; off <<= 1) {
        int w = (t >= off) ? sd[t - off] : 0;
        __syncthreads();
        sd[t] += w;
        __syncthreads();
    }
    if (t < nb) boff[t] = sd[t] - v;
}

__global__ void k_scan3(const int* __restrict__ tmp, const int* __restrict__ boff,
                        int* __restrict__ out, int n, int shift) {
    int i = blockIdx.x * 256 + threadIdx.x;
    if (i < n) out[i] = tmp[i] + boff[i >> shift];
}

// ---------------- segment offsets: 2 halves x (R edge-segs + self-seg), 128-padded ----------------
// po[s], s = h*(R+1)+r ; po[2(R+1)] = total slots

__global__ void k_offsets(const int* __restrict__ degOff, int* __restrict__ po,
                          int R, int N, int Nh, int E) {
    if (threadIdx.x == 0 && blockIdx.x == 0) {
        int acc = 0;
        for (int h = 0; h < 2; ++h) {
            int d0 = h ? Nh : 0;
            int d1 = h ? N : Nh;
            for (int r = 0; r < R; ++r) {
                int o0 = degOff[(size_t)r * N + d0];
                int o1;
                if (d1 == N) o1 = (r == R - 1) ? E : degOff[(size_t)(r + 1) * N];
                else         o1 = degOff[(size_t)r * N + d1];
                int c = o1 - o0;
                po[h * (R + 1) + r] = acc;
                acc += ((c + 127) / 128) * 128;
            }
            po[h * (R + 1) + R] = acc;
            acc += (((d1 - d0) + 127) / 128) * 128;
        }
        po[2 * (R + 1)] = acc;
    }
}

// ---------------- scatter: slotSrc in (half, relation, dst)-sorted order ----------------

__global__ void k_scatter3(const int* __restrict__ etype, const int* __restrict__ srcA,
                           const int* __restrict__ dstA, int E, int N, int R, int Nh,
                           const int* __restrict__ degOff, const int* __restrict__ po,
                           int* __restrict__ binCur, int* __restrict__ slotSrc) {
    int t = blockIdx.x * 256 + threadIdx.x;
    if (t < E) {
        int r = etype[t];
        int d = dstA[t];
        int h = (d >= Nh) ? 1 : 0;
        int bin = r * N + d;
        int rank = atomicAdd(&binCur[bin], 1);
        int base = degOff[(size_t)r * N + (h ? Nh : 0)];
        int pos = po[h * (R + 1) + r] + (degOff[bin] - base) + rank;
        slotSrc[pos] = srcA[t];
    } else if (t < E + N) {
        int n = t - E;
        int h = (n >= Nh) ? 1 : 0;
        slotSrc[po[h * (R + 1) + R] + (n - (h ? Nh : 0))] = n;
    }
}

// ---------------- fused prep: emb->bf16, weights -> bf16 k-minor PRE-SWIZZLED ----------------

__global__ void k_prep(const float* __restrict__ emb,
                       const float* __restrict__ rw1, const float* __restrict__ sl1,
                       const float* __restrict__ rw2, const float* __restrict__ sl2,
                       const float* __restrict__ pw1,
                       unsigned short* __restrict__ embb,
                       unsigned short* __restrict__ wAll1,
                       unsigned short* __restrict__ wAll2,
                       unsigned short* __restrict__ pw1T,
                       int N, int R)
{
    long t = (long)blockIdx.x * 256 + threadIdx.x;
    long u0 = (long)N * D / 4;
    if (t < u0) {
        long i = t * 4;
        f32x4 v = *(const f32x4*)(emb + i);
        unsigned a0 = (unsigned)f2b(v[0]) | ((unsigned)f2b(v[1]) << 16);
        unsigned a1 = (unsigned)f2b(v[2]) | ((unsigned)f2b(v[3]) << 16);
        uint2 o; o.x = a0; o.y = a1;
        *(uint2*)(embb + i) = o;
        return;
    }
    t -= u0;
    long uW = (long)(R + 1) * D * D;
    if (t < 2 * uW) {
        const float* rw = (t < uW) ? rw1 : rw2;
        const float* sl = (t < uW) ? sl1 : sl2;
        unsigned short* o = (t < uW) ? wAll1 : wAll2;
        long u = (t < uW) ? t : t - uW;
        int r = (int)(u >> 14);          // D*D = 16384
        int nb = (int)(u & 16383);
        int n = nb >> 7, kk = nb & 127;
        int ke = kk ^ ((n & 7) << 3);
        float v = (r < R) ? rw[((size_t)r * D + ke) * D + n] : sl[(size_t)ke * D + n];
        o[u] = f2b(v);
        return;
    }
    t -= 2 * uW;
    if (t < 3 * D * D) {
        int n = (int)(t / 384), ck = (int)(t - n * 384);
        int ch = ck >> 7, kl = (ck & 127) ^ ((n & 7) << 3);
        pw1T[t] = f2b(pw1[(size_t)(ch * 128 + kl) * 128 + n]);
    }
}

// ---------------- phase A: per-edge UNSCALED messages via MFMA (streaming y-write) ----------------

__global__ __launch_bounds__(256) void k_gemm_msg(
    const unsigned short* __restrict__ xb,
    const unsigned short* __restrict__ wAll,    // pre-swizzled, (R+1) matrices
    const int* __restrict__ slotSrc,
    const int* __restrict__ po, int R, int h,
    unsigned short* __restrict__ y)
{
    __shared__ unsigned char smB[32768];
    int tid = threadIdx.x;
    int row0 = po[h * (R + 1)] + blockIdx.x * 128;
    if (row0 >= po[(h + 1) * (R + 1)]) return;
    int s = h * (R + 1);
    while (row0 >= po[s + 1]) ++s;
    int rw = s - h * (R + 1);     // weight index (R = self)

    int lane = tid & 63, wid = tid >> 6;
    int lo = lane & 15, hi = lane >> 4;

    // ---- A preload: sequential slotSrc read, then one-level gather; issued first ----
    int r0g = wid * 32 + lo, r1g = r0g + 16;
    int sv0 = slotSrc[row0 + r0g];
    int sv1 = slotSrc[row0 + r1g];
    const unsigned short* xrow0 = xb + (size_t)sv0 * D;
    const unsigned short* xrow1 = xb + (size_t)sv1 * D;
    s16x8 a0[4], a1[4];
    #pragma unroll
    for (int ks = 0; ks < 4; ++ks) {
        a0[ks] = *(const s16x8*)(xrow0 + ks * 32 + hi * 8);
        a1[ks] = *(const s16x8*)(xrow1 + ks * 32 + hi * 8);
    }

    // ---- stage B: linear copy (weights pre-swizzled in global) ----
    {
        const int4* src = (const int4*)(wAll + (size_t)rw * D * D);
        int4* dstl = (int4*)smB;
        #pragma unroll
        for (int i = 0; i < 8; ++i) dstl[tid + i * 256] = src[tid + i * 256];
    }
    __syncthreads();

    f32x4 acc[2][8];
    #pragma unroll
    for (int a = 0; a < 2; ++a)
        #pragma unroll
        for (int b = 0; b < 8; ++b) acc[a][b] = (f32x4){0, 0, 0, 0};

    #pragma unroll
    for (int ks = 0; ks < 4; ++ks) {
        int kb = ks * 64 + hi * 16;
        #pragma unroll
        for (int n = 0; n < 8; ++n) {
            int cr = n * 16 + lo;
            s16x8 bf = *(const s16x8*)(smB + cr * 256 + (kb ^ ((cr & 7) << 4)));
            acc[0][n] = __builtin_amdgcn_mfma_f32_16x16x32_bf16(a0[ks], bf, acc[0][n], 0, 0, 0);
            acc[1][n] = __builtin_amdgcn_mfma_f32_16x16x32_bf16(a1[ks], bf, acc[1][n], 0, 0, 0);
        }
    }

    __syncthreads();   // reuse smB as bf16 store staging [128][256B]
    #pragma unroll
    for (int m2 = 0; m2 < 2; ++m2) {
        int rbase = wid * 32 + m2 * 16 + hi * 4;
        #pragma unroll
        for (int reg = 0; reg < 4; ++reg) {
            int rl = rbase + reg;
            #pragma unroll
            for (int n = 0; n < 8; ++n) {
                int byteoff = rl * 256 + (((n * 32 + (lo >> 3) * 16) ^ ((rl & 7) << 4)) + (lo & 7) * 2);
                *(unsigned short*)(smB + byteoff) = f2b(acc[m2][n][reg]);
            }
        }
    }
    __syncthreads();
    {   // streaming write: block-contiguous 32 KB at slot order
        int m = tid >> 1, half = tid & 1;
        unsigned short* dst = y + (size_t)(row0 + m) * D;
        #pragma unroll
        for (int i = 0; i < 8; ++i) {
            int c = half * 8 + i;
            int4 v = *(const int4*)(smB + m * 256 + ((c * 16) ^ ((m & 7) << 4)));
            *(int4*)(dst + c * 8) = v;
        }
    }
}

// ---------------- phase B: 9-stream segmented sum over one dst-half ----------------

template<bool RELU>
__global__ void k_reduce2(const unsigned short* __restrict__ y,
                          const int* __restrict__ degOff, const int* __restrict__ po,
                          const float* __restrict__ bias,
                          unsigned short* __restrict__ out,
                          int N, int R, int E, int h, int d0, int dcnt)
{
    __shared__ int rbase[RMAX + 1];
    int tid = threadIdx.x;
    if (tid <= R) {
        if (tid < R) rbase[tid] = po[h * (R + 1) + tid] - degOff[(size_t)tid * N + d0];
        else         rbase[R]   = po[h * (R + 1) + R] - d0;
    }
    __syncthreads();

    int team = tid >> 4, cj = tid & 15;   // 16 lanes cover one 256B row
    float b[8];
    *(f32x4*)(b)     = *(const f32x4*)(bias + cj * 8);
    *(f32x4*)(b + 4) = *(const f32x4*)(bias + cj * 8 + 4);
    int dbase = d0 + blockIdx.x * 64 + team * 4;
    int dend = d0 + dcnt;
    for (int i = 0; i < 4; ++i) {
        int d = dbase + i;
        if (d >= dend) return;
        float a[8];
        {   // self message (scale 1)
            int4 v = *(const int4*)(y + (size_t)(rbase[R] + d) * D + cj * 8);
            const unsigned short* hp = (const unsigned short*)&v;
            #pragma unroll
            for (int j = 0; j < 8; ++j) a[j] = b[j] + b2f(hp[j]);
        }
        for (int r = 0; r < R; ++r) {
            int bin = r * N + d;
            int o0 = degOff[bin];
            int o1 = (bin + 1 < R * N) ? degOff[bin + 1] : E;
            int len = o1 - o0;
            if (!len) continue;
            long start = rbase[r] + o0;
            float s8[8];
            #pragma unroll
            for (int j = 0; j < 8; ++j) s8[j] = 0.0f;
            for (int q = 0; q < len; ++q) {
                int4 v = *(const int4*)(y + (size_t)(start + q) * D + cj * 8);
                const unsigned short* hp = (const unsigned short*)&v;
                #pragma unroll
                for (int j = 0; j < 8; ++j) s8[j] += b2f(hp[j]);
            }
            float inv = 1.0f / (float)len;
            #pragma unroll
            for (int j = 0; j < 8; ++j) a[j] = fmaf(s8[j], inv, a[j]);
        }
        unsigned short o[8];
        #pragma unroll
        for (int j = 0; j < 8; ++j) {
            float v = RELU ? fmaxf(a[j], 0.0f) : a[j];
            o[j] = f2b(v);
        }
        *(int4*)(out + (size_t)d * D + cj * 8) = *(const int4*)o;
    }
}

// ---------------- pair scoring ----------------

__global__ __launch_bounds__(256) void k_score(
    const unsigned short* __restrict__ x2b,
    const int* __restrict__ drug, const int* __restrict__ dis,
    const unsigned short* __restrict__ pw1T,  // pre-swizzled [128][384]
    const float* __restrict__ pb1, const float* __restrict__ pw2,
    const float* __restrict__ pb2, float* __restrict__ outp, int P)
{
    __shared__ unsigned char smA[32768];
    __shared__ unsigned char smB[32768];
    __shared__ float pb1s[128];
    __shared__ float pw2s[128];
    int tid = threadIdx.x;
    long p0 = (long)blockIdx.x * 128;
    if (tid < 128) { pb1s[tid] = pb1[tid]; pw2s[tid] = pw2[tid]; }
    float pb2v = pb2[0];

    int lane = tid & 63, wid = tid >> 6;
    int lo = lane & 15, hi = lane >> 4;
    f32x4 acc[2][8];
    #pragma unroll
    for (int a = 0; a < 2; ++a)
        #pragma unroll
        for (int b = 0; b < 8; ++b) acc[a][b] = (f32x4){0, 0, 0, 0};

    for (int ch = 0; ch < 3; ++ch) {
        {   // stage B chunk: linear (content pre-swizzled)
            const int4* src = (const int4*)pw1T;
            int4* dstl = (int4*)smB;
            #pragma unroll
            for (int i = 0; i < 8; ++i) {
                int q = tid + i * 256;
                int n = q >> 4, c = q & 15;
                dstl[q] = src[n * 48 + ch * 16 + c];
            }
        }
        {   // stage A chunk (swizzled on write + read)
            int m = tid >> 1, half = tid & 1;
            long p = p0 + m;
            int4 z = {0, 0, 0, 0};
            if (p < P) {
                const int4* da = (const int4*)(x2b + (size_t)drug[p] * D);
                const int4* db = (const int4*)(x2b + (size_t)dis[p] * D);
                for (int c = half * 8; c < half * 8 + 8; ++c) {
                    int4 v;
                    if (ch == 0) v = da[c];
                    else if (ch == 1) v = db[c];
                    else {
                        int4 va = da[c], vb = db[c];
                        const unsigned short* ap = (const unsigned short*)&va;
                        const unsigned short* bp = (const unsigned short*)&vb;
                        unsigned short o[8];
                        #pragma unroll
                        for (int j = 0; j < 8; ++j) o[j] = f2b(b2f(ap[j]) * b2f(bp[j]));
                        v = *(const int4*)o;
                    }
                    *(int4*)(smA + m * 256 + ((c * 16) ^ ((m & 7) << 4))) = v;
                }
            } else {
                for (int c = half * 8; c < half * 8 + 8; ++c)
                    *(int4*)(smA + m * 256 + ((c * 16) ^ ((m & 7) << 4))) = z;
            }
        }
        __syncthreads();

        #pragma unroll
        for (int ks = 0; ks < 4; ++ks) {
            int kb = ks * 64 + hi * 16;
            int r0 = wid * 32 + lo, r1 = r0 + 16;
            s16x8 a0 = *(const s16x8*)(smA + r0 * 256 + (kb ^ ((r0 & 7) << 4)));
            s16x8 a1 = *(const s16x8*)(smA + r1 * 256 + (kb ^ ((r1 & 7) << 4)));
            #pragma unroll
            for (int n = 0; n < 8; ++n) {
                int cr = n * 16 + lo;
                s16x8 bf = *(const s16x8*)(smB + cr * 256 + (kb ^ ((cr & 7) << 4)));
                acc[0][n] = __builtin_amdgcn_mfma_f32_16x16x32_bf16(a0, bf, acc[0][n], 0, 0, 0);
                acc[1][n] = __builtin_amdgcn_mfma_f32_16x16x32_bf16(a1, bf, acc[1][n], 0, 0, 0);
            }
        }
        __syncthreads();
    }

    #pragma unroll
    for (int m2 = 0; m2 < 2; ++m2)
        #pragma unroll
        for (int reg = 0; reg < 4; ++reg) {
            float s = 0.0f;
            #pragma unroll
            for (int n = 0; n < 8; ++n) {
                int col = n * 16 + lo;
                float v = acc[m2][n][reg] + pb1s[col];
                v = fmaxf(v, 0.0f);
                s = fmaf(v, pw2s[col], s);
            }
            s += __shfl_xor(s, 1, 64);
            s += __shfl_xor(s, 2, 64);
            s += __shfl_xor(s, 4, 64);
            s += __shfl_xor(s, 8, 64);
            long p = p0 + wid * 32 + m2 * 16 + hi * 4 + reg;
            if (lo == 0 && p < P) outp[p] = s + pb2v;
        }
}

// ---------------- launch ----------------

extern "C" void kernel_launch(void* const* d_in, const int* in_sizes, int n_in,
                              void* d_out, int out_size, void* d_ws, size_t ws_size,
                              hipStream_t stream) {
    const int*   edge_index = (const int*)d_in[0];
    const int*   edge_type  = (const int*)d_in[1];
    const int*   drug       = (const int*)d_in[2];
    const int*   dis        = (const int*)d_in[3];
    const float* emb        = (const float*)d_in[4];
    const float* rw1        = (const float*)d_in[5];
    const float* sl1        = (const float*)d_in[6];
    const float* b1         = (const float*)d_in[7];
    const float* rw2        = (const float*)d_in[8];
    const float* sl2        = (const float*)d_in[9];
    const float* b2         = (const float*)d_in[10];
    const float* pw1        = (const float*)d_in[11];
    const float* pb1        = (const float*)d_in[12];
    const float* pw2        = (const float*)d_in[13];
    const float* pb2        = (const float*)d_in[14];

    const int E = in_sizes[1];
    const int P = in_sizes[2];
    const int N = in_sizes[4] / D;
    const int R = in_sizes[5] / (D * D);
    const int Nh = (N + 1) / 2;

    const int* srcA = edge_index;
    const int* dstA = edge_index + E;

    const int slotN = E + N + 128 * (2 * R + 4);

    char* ws = (char*)d_ws;
    unsigned short* embb = (unsigned short*)ws; ws += (size_t)N * D * 2;   // aliased as x2b
    unsigned short* x1b  = (unsigned short*)ws; ws += (size_t)N * D * 2;
    unsigned short* y    = (unsigned short*)ws; ws += (size_t)slotN * D * 2;
    unsigned short* wAll1 = (unsigned short*)ws; ws += (size_t)(R + 1) * D * D * 2;
    unsigned short* wAll2 = (unsigned short*)ws; ws += (size_t)(R + 1) * D * D * 2;
    unsigned short* pw1T  = (unsigned short*)ws; ws += (size_t)3 * D * D * 2;
    // zero region (single memset): deg | binCur | slotSrc
    int*   deg     = (int*)ws;   ws += (size_t)R * N * 4;
    int*   binCur  = (int*)ws;   ws += (size_t)R * N * 4;
    int*   slotSrc = (int*)ws;   ws += (size_t)slotN * 4;
    size_t zbytes = (size_t)(2 * R * N + slotN) * 4;
    int* degOff  = (int*)ws; ws += (size_t)R * N * 4;
    int* bsum    = (int*)ws; ws += 256 * 4;
    int* boff    = (int*)ws; ws += 256 * 4;
    int* po      = (int*)ws; ws += 256;
    unsigned short* x2b = embb;

    hipMemsetAsync(deg, 0, zbytes, stream);

    // fused prep (emb->bf16, weights pre-swizzled bf16)
    long u0 = (long)N * D / 4;
    long uW = (long)(R + 1) * D * D;
    long utot = u0 + 2 * uW + 3 * D * D;
    k_prep<<<(int)((utot + 255) / 256), 256, 0, stream>>>(emb, rw1, sl1, rw2, sl2, pw1,
                                                          embb, wAll1, wAll2, pw1T, N, R);

    k_count2<<<(E + 255) / 256, 256, 0, stream>>>(edge_type, dstA, E, N, deg);

    // exclusive scan of deg over R*N -> degOff
    int nbS = (R * N + 4095) / 4096;
    k_scan_blk<16><<<nbS, 256, 0, stream>>>(deg, degOff, bsum, R * N);
    k_scan2<<<1, 256, 0, stream>>>(bsum, boff, nbS);
    k_scan3<<<(R * N + 255) / 256, 256, 0, stream>>>(degOff, boff, degOff, R * N, 12);

    k_offsets<<<1, 1, 0, stream>>>(degOff, po, R, N, Nh, E);

    // fill slotSrc in (half,relation,dst)-sorted order (+ self rows)
    k_scatter3<<<(E + N + 255) / 256, 256, 0, stream>>>(edge_type, srcA, dstA, E, N, R,
                                                        Nh, degOff, po, binCur, slotSrc);

    int gridMh = (E + 127) / 128 + (Nh + 127) / 128 + R + 2;
    int gridR0 = (Nh + 63) / 64;
    int gridR1 = (N - Nh + 63) / 64;

    // layer 1 (half-pipelined so each half's y stays L3-resident for its reduce)
    k_gemm_msg<<<gridMh, 256, 0, stream>>>(embb, wAll1, slotSrc, po, R, 0, y);
    k_reduce2<true><<<gridR0, 256, 0, stream>>>(y, degOff, po, b1, x1b, N, R, E, 0, 0, Nh);
    k_gemm_msg<<<gridMh, 256, 0, stream>>>(embb, wAll1, slotSrc, po, R, 1, y);
    k_reduce2<true><<<gridR1, 256, 0, stream>>>(y, degOff, po, b1, x1b, N, R, E, 1, Nh, N - Nh);
    // layer 2
    k_gemm_msg<<<gridMh, 256, 0, stream>>>(x1b, wAll2, slotSrc, po, R, 0, y);
    k_reduce2<false><<<gridR0, 256, 0, stream>>>(y, degOff, po, b2, x2b, N, R, E, 0, 0, Nh);
    k_gemm_msg<<<gridMh, 256, 0, stream>>>(x1b, wAll2, slotSrc, po, R, 1, y);
    k_reduce2<false><<<gridR1, 256, 0, stream>>>(y, degOff, po, b2, x2b, N, R, E, 1, Nh, N - Nh);
    // scoring
    k_score<<<(P + 127) / 128, 256, 0, stream>>>(x2b, drug, dis, pw1T, pb1, pw2, pb2,
                                                 (float*)d_out, P);
}

// Round 10
// 520.609 us; speedup vs baseline: 1.0857x; 1.0857x over previous
//
#include <hip/hip_runtime.h>

#define D 128

typedef short s16x8 __attribute__((ext_vector_type(8)));
typedef float f32x4 __attribute__((ext_vector_type(4)));

__device__ inline unsigned short f2b(float f) {
    unsigned u = __builtin_bit_cast(unsigned, f);
    unsigned r = (u + 0x7FFFu + ((u >> 16) & 1u)) >> 16;
    return (unsigned short)r;
}
__device__ inline float b2f(unsigned short h) {
    unsigned u = ((unsigned)h) << 16;
    return __builtin_bit_cast(float, u);
}

// ---------------- histogram: deg[r*N+dst] ----------------

__global__ void k_count2(const int* __restrict__ etype, const int* __restrict__ dstA,
                         int E, int N, int* __restrict__ deg) {
    int e = blockIdx.x * blockDim.x + threadIdx.x;
    if (e < E) atomicAdd(&deg[etype[e] * N + dstA[e]], 1);
}

// ---------------- exclusive scan over R*N ----------------

template<int VPT>
__global__ void k_scan_blk(const int* __restrict__ in, int* __restrict__ tmp,
                           int* __restrict__ bsum, int n) {
    __shared__ int sd[256];
    int t = threadIdx.x;
    long base = (long)blockIdx.x * (256 * VPT) + (long)t * VPT;
    int s[VPT];
    int tsum = 0;
    #pragma unroll
    for (int k = 0; k < VPT; ++k) { s[k] = (base + k < n) ? in[base + k] : 0; tsum += s[k]; }
    sd[t] = tsum;
    __syncthreads();
    for (int off = 1; off < 256; off <<= 1) {
        int v = (t >= off) ? sd[t - off] : 0;
        __syncthreads();
        sd[t] += v;
        __syncthreads();
    }
    int run = sd[t] - tsum;
    #pragma unroll
    for (int k = 0; k < VPT; ++k) { if (base + k < n) tmp[base + k] = run; run += s[k]; }
    if (t == 255) bsum[blockIdx.x] = sd[255];
}

__global__ void k_scan2(const int* __restrict__ bsum, int* __restrict__ boff, int nb) {
    __shared__ int sd[256];
    int t = threadIdx.x;
    int v = (t < nb) ? bsum[t] : 0;
    sd[t] = v;
    __syncthreads();
    for (int off = 1; off < 256; off <<= 1) {
        int w = (t >= off) ? sd[t - off] : 0;
        __syncthreads();
        sd[t] += w;
        __syncthreads();
    }
    if (t < nb) boff[t] = sd[t] - v;
}

__global__ void k_scan3(const int* __restrict__ tmp, const int* __restrict__ boff,
                        int* __restrict__ out, int n, int shift) {
    int i = blockIdx.x * 256 + threadIdx.x;
    if (i < n) out[i] = tmp[i] + boff[i >> shift];
}

// ---------------- scatter: slotSrc in (relation,dst)-sorted order (no padding) ----------------

__global__ void k_scatter(const int* __restrict__ etype, const int* __restrict__ srcA,
                          const int* __restrict__ dstA, int E, int N,
                          const int* __restrict__ degOff, int* __restrict__ binCur,
                          int* __restrict__ slotSrc) {
    int e = blockIdx.x * 256 + threadIdx.x;
    if (e < E) {
        int bin = etype[e] * N + dstA[e];
        int rank = atomicAdd(&binCur[bin], 1);
        slotSrc[degOff[bin] + rank] = srcA[e];
    }
}

// ---------------- fused prep: emb->bf16, weights -> bf16 k-minor PRE-SWIZZLED ----------------

__global__ void k_prep(const float* __restrict__ emb,
                       const float* __restrict__ rw1, const float* __restrict__ sl1,
                       const float* __restrict__ rw2, const float* __restrict__ sl2,
                       const float* __restrict__ pw1,
                       unsigned short* __restrict__ embb,
                       unsigned short* __restrict__ wAll1,
                       unsigned short* __restrict__ wAll2,
                       unsigned short* __restrict__ pw1T,
                       int N, int R)
{
    long t = (long)blockIdx.x * 256 + threadIdx.x;
    long u0 = (long)N * D / 4;
    if (t < u0) {
        long i = t * 4;
        f32x4 v = *(const f32x4*)(emb + i);
        unsigned a0 = (unsigned)f2b(v[0]) | ((unsigned)f2b(v[1]) << 16);
        unsigned a1 = (unsigned)f2b(v[2]) | ((unsigned)f2b(v[3]) << 16);
        uint2 o; o.x = a0; o.y = a1;
        *(uint2*)(embb + i) = o;
        return;
    }
    t -= u0;
    long uW = (long)(R + 1) * D * D;
    if (t < 2 * uW) {
        const float* rw = (t < uW) ? rw1 : rw2;
        const float* sl = (t < uW) ? sl1 : sl2;
        unsigned short* o = (t < uW) ? wAll1 : wAll2;
        long u = (t < uW) ? t : t - uW;
        int r = (int)(u >> 14);          // D*D = 16384
        int nb = (int)(u & 16383);
        int n = nb >> 7, kk = nb & 127;
        int ke = kk ^ ((n & 7) << 3);
        float v = (r < R) ? rw[((size_t)r * D + ke) * D + n] : sl[(size_t)ke * D + n];
        o[u] = f2b(v);
        return;
    }
    t -= 2 * uW;
    if (t < 3 * D * D) {
        int n = (int)(t / 384), ck = (int)(t - n * 384);
        int ch = ck >> 7, kl = (ck & 127) ^ ((n & 7) << 3);
        pw1T[t] = f2b(pw1[(size_t)(ch * 128 + kl) * 128 + n]);
    }
}

// ---------------- fused RGCN layer: block owns 128 dsts, loops 9 weight mats ----------------
// out[d] = bf16( [relu]( bias + x[d]@sl + sum_r (1/deg_{r,d}) * sum_{src in N_r(d)} x[src]@rw_r ) )

template<bool RELU>
__global__ __launch_bounds__(256) void k_fused(
    const unsigned short* __restrict__ xb,     // [N][D] bf16
    const unsigned short* __restrict__ wAll,   // (R+1) pre-swizzled 128x128 bf16 mats
    const int* __restrict__ slotSrc,           // [E], (r,dst)-sorted
    const int* __restrict__ degOff,            // exclusive scan of deg over R*N
    const float* __restrict__ bias,
    unsigned short* __restrict__ out,
    int N, int R, int E)
{
    __shared__ unsigned char smB[32768];
    __shared__ unsigned char smM[32768];
    int tid = threadIdx.x;
    int d0 = blockIdx.x * 128;
    int dmax = (d0 + 128 < N) ? d0 + 128 : N;

    int lane = tid & 63, wid = tid >> 6;
    int lo = lane & 15, hi = lane >> 4;
    int m = tid >> 1, ch = tid & 1;
    int dmine = d0 + m;

    float a[64];
    #pragma unroll
    for (int j = 0; j < 64; ++j) a[j] = 0.0f;

    for (int r = 0; r <= R; ++r) {
        int s0, cnt;
        if (r < R) {
            s0 = degOff[r * N + d0];
            int b1 = r * N + dmax;
            int s1 = (b1 < R * N) ? degOff[b1] : E;
            cnt = s1 - s0;
            if (cnt == 0) continue;
        } else {
            s0 = 0;
            cnt = dmax - d0;        // self rows
        }

        // ---- stage B_r (linear copy; content pre-swizzled) ----
        {
            const int4* src = (const int4*)(wAll + (size_t)r * D * D);
            int4* dstl = (int4*)smB;
            #pragma unroll
            for (int i = 0; i < 8; ++i) dstl[tid + i * 256] = src[tid + i * 256];
        }
        __syncthreads();

        for (int c0 = 0; c0 < cnt; c0 += 128) {
            // ---- A gather (registers, issued before sync) ----
            int i0 = c0 + wid * 32 + lo;
            int i1 = i0 + 16;
            int ci0 = (i0 < cnt) ? i0 : cnt - 1;
            int ci1 = (i1 < cnt) ? i1 : cnt - 1;
            int sv0, sv1;
            if (r < R) { sv0 = slotSrc[s0 + ci0]; sv1 = slotSrc[s0 + ci1]; }
            else       { sv0 = d0 + ci0;          sv1 = d0 + ci1; }
            const unsigned short* xr0 = xb + (size_t)sv0 * D;
            const unsigned short* xr1 = xb + (size_t)sv1 * D;
            s16x8 af0[4], af1[4];
            #pragma unroll
            for (int ks = 0; ks < 4; ++ks) {
                af0[ks] = *(const s16x8*)(xr0 + ks * 32 + hi * 8);
                af1[ks] = *(const s16x8*)(xr1 + ks * 32 + hi * 8);
            }

            f32x4 acc[2][8];
            #pragma unroll
            for (int q = 0; q < 2; ++q)
                #pragma unroll
                for (int n = 0; n < 8; ++n) acc[q][n] = (f32x4){0, 0, 0, 0};

            #pragma unroll
            for (int ks = 0; ks < 4; ++ks) {
                int kb = ks * 64 + hi * 16;
                #pragma unroll
                for (int n = 0; n < 8; ++n) {
                    int cr = n * 16 + lo;
                    s16x8 bf = *(const s16x8*)(smB + cr * 256 + (kb ^ ((cr & 7) << 4)));
                    acc[0][n] = __builtin_amdgcn_mfma_f32_16x16x32_bf16(af0[ks], bf, acc[0][n], 0, 0, 0);
                    acc[1][n] = __builtin_amdgcn_mfma_f32_16x16x32_bf16(af1[ks], bf, acc[1][n], 0, 0, 0);
                }
            }

            __syncthreads();   // prior accumulate reads of smM complete
            // ---- stage C (bf16, swizzled) ----
            #pragma unroll
            for (int m2 = 0; m2 < 2; ++m2) {
                int rbase = wid * 32 + m2 * 16 + hi * 4;
                #pragma unroll
                for (int reg = 0; reg < 4; ++reg) {
                    int rl = rbase + reg;
                    #pragma unroll
                    for (int n = 0; n < 8; ++n) {
                        int byteoff = rl * 256 + (((n * 32 + (lo >> 3) * 16) ^ ((rl & 7) << 4)) + (lo & 7) * 2);
                        *(unsigned short*)(smM + byteoff) = f2b(acc[m2][n][reg]);
                    }
                }
            }
            __syncthreads();

            // ---- accumulate own dst's run from this chunk ----
            if (dmine < N) {
                int st, en; float inv;
                if (r < R) {
                    int bin = r * N + dmine;
                    st = degOff[bin];
                    en = (bin + 1 < R * N) ? degOff[bin + 1] : E;
                    inv = (en > st) ? 1.0f / (float)(en - st) : 0.0f;
                } else {
                    st = m; en = m + 1; inv = 1.0f;
                }
                int loI = st > s0 + c0 ? st : s0 + c0;
                int hiI = en < s0 + c0 + 128 ? en : s0 + c0 + 128;
                for (int slot = loI; slot < hiI; ++slot) {
                    int rl = slot - (s0 + c0);
                    #pragma unroll
                    for (int g = 0; g < 8; ++g) {
                        int c = ch * 8 + g;
                        int4 v = *(const int4*)(smM + rl * 256 + ((c * 16) ^ ((rl & 7) << 4)));
                        const unsigned short* hp = (const unsigned short*)&v;
                        #pragma unroll
                        for (int k = 0; k < 8; ++k)
                            a[g * 8 + k] = fmaf(b2f(hp[k]), inv, a[g * 8 + k]);
                    }
                }
            }
            __syncthreads();   // accumulate done before next chunk overwrites smM
        }
    }

    // ---- epilogue ----
    if (dmine < N) {
        #pragma unroll
        for (int g = 0; g < 8; ++g) {
            unsigned short o8[8];
            #pragma unroll
            for (int k = 0; k < 8; ++k) {
                float v = a[g * 8 + k] + bias[ch * 64 + g * 8 + k];
                if (RELU) v = fmaxf(v, 0.0f);
                o8[k] = f2b(v);
            }
            *(int4*)(out + (size_t)dmine * D + ch * 64 + g * 8) = *(const int4*)o8;
        }
    }
}

// ---------------- pair scoring ----------------

__global__ __launch_bounds__(256) void k_score(
    const unsigned short* __restrict__ x2b,
    const int* __restrict__ drug, const int* __restrict__ dis,
    const unsigned short* __restrict__ pw1T,  // pre-swizzled [128][384]
    const float* __restrict__ pb1, const float* __restrict__ pw2,
    const float* __restrict__ pb2, float* __restrict__ outp, int P)
{
    __shared__ unsigned char smA[32768];
    __shared__ unsigned char smB[32768];
    __shared__ float pb1s[128];
    __shared__ float pw2s[128];
    int tid = threadIdx.x;
    long p0 = (long)blockIdx.x * 128;
    if (tid < 128) { pb1s[tid] = pb1[tid]; pw2s[tid] = pw2[tid]; }
    float pb2v = pb2[0];

    int lane = tid & 63, wid = tid >> 6;
    int lo = lane & 15, hi = lane >> 4;
    f32x4 acc[2][8];
    #pragma unroll
    for (int q = 0; q < 2; ++q)
        #pragma unroll
        for (int b = 0; b < 8; ++b) acc[q][b] = (f32x4){0, 0, 0, 0};

    for (int chn = 0; chn < 3; ++chn) {
        {   // stage B chunk: linear (content pre-swizzled)
            const int4* src = (const int4*)pw1T;
            int4* dstl = (int4*)smB;
            #pragma unroll
            for (int i = 0; i < 8; ++i) {
                int q = tid + i * 256;
                int n = q >> 4, c = q & 15;
                dstl[q] = src[n * 48 + chn * 16 + c];
            }
        }
        {   // stage A chunk (swizzled on write + read)
            int m = tid >> 1, half = tid & 1;
            long p = p0 + m;
            int4 z = {0, 0, 0, 0};
            if (p < P) {
                const int4* da = (const int4*)(x2b + (size_t)drug[p] * D);
                const int4* db = (const int4*)(x2b + (size_t)dis[p] * D);
                for (int c = half * 8; c < half * 8 + 8; ++c) {
                    int4 v;
                    if (chn == 0) v = da[c];
                    else if (chn == 1) v = db[c];
                    else {
                        int4 va = da[c], vb = db[c];
                        const unsigned short* ap = (const unsigned short*)&va;
                        const unsigned short* bp = (const unsigned short*)&vb;
                        unsigned short o[8];
                        #pragma unroll
                        for (int j = 0; j < 8; ++j) o[j] = f2b(b2f(ap[j]) * b2f(bp[j]));
                        v = *(const int4*)o;
                    }
                    *(int4*)(smA + m * 256 + ((c * 16) ^ ((m & 7) << 4))) = v;
                }
            } else {
                for (int c = half * 8; c < half * 8 + 8; ++c)
                    *(int4*)(smA + m * 256 + ((c * 16) ^ ((m & 7) << 4))) = z;
            }
        }
        __syncthreads();

        #pragma unroll
        for (int ks = 0; ks < 4; ++ks) {
            int kb = ks * 64 + hi * 16;
            int r0 = wid * 32 + lo, r1 = r0 + 16;
            s16x8 a0 = *(const s16x8*)(smA + r0 * 256 + (kb ^ ((r0 & 7) << 4)));
            s16x8 a1 = *(const s16x8*)(smA + r1 * 256 + (kb ^ ((r1 & 7) << 4)));
            #pragma unroll
            for (int n = 0; n < 8; ++n) {
                int cr = n * 16 + lo;
                s16x8 bf = *(const s16x8*)(smB + cr * 256 + (kb ^ ((cr & 7) << 4)));
                acc[0][n] = __builtin_amdgcn_mfma_f32_16x16x32_bf16(a0, bf, acc[0][n], 0, 0, 0);
                acc[1][n] = __builtin_amdgcn_mfma_f32_16x16x32_bf16(a1, bf, acc[1][n], 0, 0, 0);
            }
        }
        __syncthreads();
    }

    #pragma unroll
    for (int m2 = 0; m2 < 2; ++m2)
        #pragma unroll
        for (int reg = 0; reg < 4; ++reg) {
            float s = 0.0f;
            #pragma unroll
            for (int n = 0; n < 8; ++n) {
                int col = n * 16 + lo;
                float v = acc[m2][n][reg] + pb1s[col];
                v = fmaxf(v, 0.0f);
                s = fmaf(v, pw2s[col], s);
            }
            s += __shfl_xor(s, 1, 64);
            s += __shfl_xor(s, 2, 64);
            s += __shfl_xor(s, 4, 64);
            s += __shfl_xor(s, 8, 64);
            long p = p0 + wid * 32 + m2 * 16 + hi * 4 + reg;
            if (lo == 0 && p < P) outp[p] = s + pb2v;
        }
}

// ---------------- launch ----------------

extern "C" void kernel_launch(void* const* d_in, const int* in_sizes, int n_in,
                              void* d_out, int out_size, void* d_ws, size_t ws_size,
                              hipStream_t stream) {
    const int*   edge_index = (const int*)d_in[0];
    const int*   edge_type  = (const int*)d_in[1];
    const int*   drug       = (const int*)d_in[2];
    const int*   dis        = (const int*)d_in[3];
    const float* emb        = (const float*)d_in[4];
    const float* rw1        = (const float*)d_in[5];
    const float* sl1        = (const float*)d_in[6];
    const float* b1         = (const float*)d_in[7];
    const float* rw2        = (const float*)d_in[8];
    const float* sl2        = (const float*)d_in[9];
    const float* b2         = (const float*)d_in[10];
    const float* pw1        = (const float*)d_in[11];
    const float* pb1        = (const float*)d_in[12];
    const float* pw2        = (const float*)d_in[13];
    const float* pb2        = (const float*)d_in[14];

    const int E = in_sizes[1];
    const int P = in_sizes[2];
    const int N = in_sizes[4] / D;
    const int R = in_sizes[5] / (D * D);

    const int* srcA = edge_index;
    const int* dstA = edge_index + E;

    char* ws = (char*)d_ws;
    unsigned short* embb = (unsigned short*)ws; ws += (size_t)N * D * 2;   // aliased as x2b
    unsigned short* x1b  = (unsigned short*)ws; ws += (size_t)N * D * 2;
    unsigned short* wAll1 = (unsigned short*)ws; ws += (size_t)(R + 1) * D * D * 2;
    unsigned short* wAll2 = (unsigned short*)ws; ws += (size_t)(R + 1) * D * D * 2;
    unsigned short* pw1T  = (unsigned short*)ws; ws += (size_t)3 * D * D * 2;
    // zero region (single memset): deg | binCur
    int* deg     = (int*)ws; ws += (size_t)R * N * 4;
    int* binCur  = (int*)ws; ws += (size_t)R * N * 4;
    size_t zbytes = (size_t)(2 * R * N) * 4;
    int* slotSrc = (int*)ws; ws += (size_t)E * 4;
    int* degOff  = (int*)ws; ws += (size_t)R * N * 4;
    int* bsum    = (int*)ws; ws += 256 * 4;
    int* boff    = (int*)ws; ws += 256 * 4;
    unsigned short* x2b = embb;

    hipMemsetAsync(deg, 0, zbytes, stream);

    // fused prep (emb->bf16, weights pre-swizzled bf16)
    long u0 = (long)N * D / 4;
    long uW = (long)(R + 1) * D * D;
    long utot = u0 + 2 * uW + 3 * D * D;
    k_prep<<<(int)((utot + 255) / 256), 256, 0, stream>>>(emb, rw1, sl1, rw2, sl2, pw1,
                                                          embb, wAll1, wAll2, pw1T, N, R);

    k_count2<<<(E + 255) / 256, 256, 0, stream>>>(edge_type, dstA, E, N, deg);

    // exclusive scan of deg over R*N -> degOff
    int nbS = (R * N + 4095) / 4096;
    k_scan_blk<16><<<nbS, 256, 0, stream>>>(deg, degOff, bsum, R * N);
    k_scan2<<<1, 256, 0, stream>>>(bsum, boff, nbS);
    k_scan3<<<(R * N + 255) / 256, 256, 0, stream>>>(degOff, boff, degOff, R * N, 12);

    // fill slotSrc in (relation,dst)-sorted order
    k_scatter<<<(E + 255) / 256, 256, 0, stream>>>(edge_type, srcA, dstA, E, N,
                                                   degOff, binCur, slotSrc);

    int gridF = (N + 127) / 128;

    // layer 1 + layer 2 fully fused (no intermediate message buffer)
    k_fused<true><<<gridF, 256, 0, stream>>>(embb, wAll1, slotSrc, degOff, b1, x1b, N, R, E);
    k_fused<false><<<gridF, 256, 0, stream>>>(x1b, wAll2, slotSrc, degOff, b2, x2b, N, R, E);

    // scoring
    k_score<<<(P + 127) / 128, 256, 0, stream>>>(x2b, drug, dis, pw1T, pb1, pw2, pb2,
                                                 (float*)d_out, P);
}